// Round 1
// baseline (459.732 us; speedup 1.0000x reference)
//
#include <hip/hip_runtime.h>
#include <hip/hip_bf16.h>

#define DM 512
#define DH 64
#define NH 8
#define NP 2048
#define NB 2
#define NROWS (NB*NP)

typedef short s16x8 __attribute__((ext_vector_type(8)));
typedef float f32x4 __attribute__((ext_vector_type(4)));

__device__ __forceinline__ unsigned short f2bf(float f){
  __hip_bfloat16 h = __float2bfloat16(f);
  return __builtin_bit_cast(unsigned short, h);
}

__device__ __forceinline__ f32x4 mfma16(s16x8 a, s16x8 b, f32x4 c){
  return __builtin_amdgcn_mfma_f32_16x16x32_bf16(a, b, c, 0, 0, 0);
}

__device__ __forceinline__ void store8(unsigned short* dst, const unsigned short* v){
  uint4 u;
  u.x = (unsigned)v[0] | ((unsigned)v[1]<<16);
  u.y = (unsigned)v[2] | ((unsigned)v[3]<<16);
  u.z = (unsigned)v[4] | ((unsigned)v[5]<<16);
  u.w = (unsigned)v[6] | ((unsigned)v[7]<<16);
  *(uint4*)dst = u;
}

// ---------------- prep: x fp32 -> bf16 ----------------
__global__ void prep_x(const float* __restrict__ x, unsigned short* __restrict__ xb){
  int i = (blockIdx.x*256 + threadIdx.x)*4;
  float4 v = *(const float4*)(x + i);
  unsigned short s0=f2bf(v.x), s1=f2bf(v.y), s2=f2bf(v.z), s3=f2bf(v.w);
  uint2 u; u.x = (unsigned)s0 | ((unsigned)s1<<16); u.y = (unsigned)s2 | ((unsigned)s3<<16);
  *(uint2*)(xb + i) = u;
}

// ---------------- prep: transpose weights to [n][k] bf16 ----------------
// WT[z], z=0:Wq 1:Wk 2:Wv 3:Wproj
__global__ void prep_w(const float* __restrict__ Wq, const float* __restrict__ Wk,
                       const float* __restrict__ Wv, const float* __restrict__ Wp,
                       unsigned short* __restrict__ WT){
  __shared__ float t[64][65];
  const float* W = (blockIdx.z==0)?Wq:(blockIdx.z==1)?Wk:(blockIdx.z==2)?Wv:Wp;
  const int k0 = blockIdx.x*64, n0 = blockIdx.y*64;
  const int c = threadIdx.x&63, rq = threadIdx.x>>6;
  #pragma unroll
  for(int rr=0;rr<16;rr++){
    int kl = rq*16+rr;
    t[kl][c] = W[(size_t)(k0+kl)*DM + n0 + c];
  }
  __syncthreads();
  unsigned short* o = WT + (size_t)blockIdx.z*DM*DM;
  #pragma unroll
  for(int rr=0;rr<16;rr++){
    int nl = rq*16+rr;
    o[(size_t)(n0+nl)*DM + k0 + c] = f2bf(t[c][nl]);
  }
}

// ---------------- QKV projection GEMM ----------------
// z=0: Qs (scaled 1/8) [b][h][p][d]; z=1: K [b][h][p][d]; z=2: Vt [b][h][d][p]
__global__ __launch_bounds__(256) void qkv_kern(const unsigned short* __restrict__ xb,
    const unsigned short* __restrict__ WT,
    unsigned short* __restrict__ Qs, unsigned short* __restrict__ Kk,
    unsigned short* __restrict__ Vt){
  const int z = blockIdx.z, h = blockIdx.y;
  const int R0 = blockIdx.x*64;
  const int tid = threadIdx.x;
  const int w = tid>>6, lane = tid&63, m = lane&15, q = lane>>4;
  const unsigned short* Wz = WT + (size_t)z*DM*DM;
  f32x4 acc[4] = {};
  const unsigned short* arow = xb + (size_t)(R0 + w*16 + m)*DM + q*8;
  const unsigned short* brow = Wz + (size_t)(h*64 + m)*DM + q*8;
  for(int k=0;k<DM;k+=32){
    s16x8 A = *(const s16x8*)(arow + k);
    #pragma unroll
    for(int nt=0;nt<4;nt++){
      s16x8 B = *(const s16x8*)(brow + (size_t)nt*16*DM + k);
      acc[nt] = mfma16(A, B, acc[nt]);
    }
  }
  __shared__ float t[64][65];
  const float scale = (z==0) ? 0.125f : 1.0f;
  #pragma unroll
  for(int nt=0;nt<4;nt++)
    #pragma unroll
    for(int r=0;r<4;r++)
      t[w*16 + q*4 + r][nt*16 + m] = acc[nt][r]*scale;
  __syncthreads();
  const int b = R0>>11, p0 = R0&2047;
  unsigned short vbuf[16];
  if(z<2){
    unsigned short* outp = (z==0)? Qs : Kk;
    int pl = tid>>2, c0 = (tid&3)*16;
    #pragma unroll
    for(int i=0;i<16;i++) vbuf[i]=f2bf(t[pl][c0+i]);
    unsigned short* dst = outp + ((size_t)(b*NH+h)*NP + p0+pl)*DH + c0;
    store8(dst, vbuf); store8(dst+8, vbuf+8);
  } else {
    int d = tid>>2, c0 = (tid&3)*16;
    #pragma unroll
    for(int i=0;i<16;i++) vbuf[i]=f2bf(t[c0+i][d]);
    unsigned short* dst = Vt + ((size_t)(b*NH+h)*DH + d)*NP + p0 + c0;
    store8(dst, vbuf); store8(dst+8, vbuf+8);
  }
}

// ---------------- fused talking-heads attention ----------------
// block: 16 q-rows, all 8 heads, 4 waves; wave w owns j-subtile w*16 within each 64-wide j-tile.
// sweep 1: l_g(i) = sum_j exp(sum_h W1[h,g] * (q_h . k_h))   (no max needed: |S| < ~10)
// sweep 2: A2_g = sum_h W2[h,g] * exp(S1_h)/l_h ; O_g += A2_g @ V_g
__global__ __launch_bounds__(256,1) void attn_kern(const unsigned short* __restrict__ Qs,
    const unsigned short* __restrict__ Kk, const unsigned short* __restrict__ Vt,
    const float* __restrict__ W1, const float* __restrict__ W2,
    unsigned short* __restrict__ O){
  const int b = blockIdx.y;
  const int i0 = blockIdx.x*16;
  const int tid = threadIdx.x;
  const int w = tid>>6, lane = tid&63, m = lane&15, q = lane>>4;

  __shared__ float Lred[4][NH][16];
  __shared__ __align__(16) unsigned short LA2[NH][16][72];  // pad 64->72: 2-way-max banks, 16B-aligned rows

  float w1[8][8], w2[8][8];
  #pragma unroll
  for(int h=0;h<8;h++)
    #pragma unroll
    for(int g=0;g<8;g++){ w1[h][g]=W1[h*8+g]; w2[h][g]=W2[h*8+g]; }

  const unsigned short* Qb = Qs + (size_t)b*NH*NP*DH;
  const unsigned short* Kb = Kk + (size_t)b*NH*NP*DH;
  const unsigned short* Vb = Vt + (size_t)b*NH*DH*NP;

  // Q fragments (A-layout: row m = lane&15, k = q*8..): resident for whole kernel
  s16x8 Qf[8][2];
  #pragma unroll
  for(int h=0;h<8;h++){
    const unsigned short* qp = Qb + ((size_t)h*NP + i0 + m)*DH + q*8;
    Qf[h][0] = *(const s16x8*)(qp);
    Qf[h][1] = *(const s16x8*)(qp + 32);
  }

  // ---- sweep 1: softmax denominators ----
  f32x4 lacc[8] = {};
  for(int jt=0; jt<NP/64; jt++){
    const int j0 = jt*64 + w*16;
    f32x4 S[8];
    #pragma unroll
    for(int h=0;h<8;h++){
      const unsigned short* kp = Kb + ((size_t)h*NP + j0 + m)*DH + q*8;
      s16x8 k0 = *(const s16x8*)(kp);
      s16x8 k1 = *(const s16x8*)(kp + 32);
      f32x4 z = {};
      z = mfma16(Qf[h][0], k0, z);
      S[h] = mfma16(Qf[h][1], k1, z);
    }
    #pragma unroll
    for(int g=0;g<8;g++){
      f32x4 s1 = S[0]*w1[0][g];
      #pragma unroll
      for(int h=1;h<8;h++) s1 += S[h]*w1[h][g];
      #pragma unroll
      for(int r=0;r<4;r++) lacc[g][r] += __expf(s1[r]);
    }
  }
  // reduce over the 16 column-lanes (cols = lane&15; rows = q*4+r)
  #pragma unroll
  for(int g=0;g<8;g++)
    #pragma unroll
    for(int r=0;r<4;r++){
      float v = lacc[g][r];
      v += __shfl_xor(v,1); v += __shfl_xor(v,2); v += __shfl_xor(v,4); v += __shfl_xor(v,8);
      lacc[g][r]=v;
    }
  if(m==0){
    #pragma unroll
    for(int g=0;g<8;g++)
      #pragma unroll
      for(int r=0;r<4;r++) Lred[w][g][q*4+r]=lacc[g][r];
  }
  __syncthreads();
  f32x4 rl[8];
  #pragma unroll
  for(int g=0;g<8;g++)
    #pragma unroll
    for(int r=0;r<4;r++){
      float v = Lred[0][g][q*4+r]+Lred[1][g][q*4+r]+Lred[2][g][q*4+r]+Lred[3][g][q*4+r];
      rl[g][r] = 1.0f/v;
    }

  // ---- sweep 2: P, W2-mix, PV ----
  f32x4 Oacc[2][4] = {};
  for(int jt=0; jt<NP/64; jt++){
    const int j0 = jt*64 + w*16;
    f32x4 S[8];
    #pragma unroll
    for(int h=0;h<8;h++){
      const unsigned short* kp = Kb + ((size_t)h*NP + j0 + m)*DH + q*8;
      s16x8 k0 = *(const s16x8*)(kp);
      s16x8 k1 = *(const s16x8*)(kp + 32);
      f32x4 z = {};
      z = mfma16(Qf[h][0], k0, z);
      S[h] = mfma16(Qf[h][1], k1, z);
    }
    f32x4 Pn[8];
    #pragma unroll
    for(int g=0;g<8;g++){
      f32x4 s1 = S[0]*w1[0][g];
      #pragma unroll
      for(int h=1;h<8;h++) s1 += S[h]*w1[h][g];
      #pragma unroll
      for(int r=0;r<4;r++) Pn[g][r] = __expf(s1[r]) * rl[g][r];
    }
    f32x4 A2[8];
    #pragma unroll
    for(int go=0;go<8;go++){
      f32x4 a = Pn[0]*w2[0][go];
      #pragma unroll
      for(int h=1;h<8;h++) a += Pn[h]*w2[h][go];
      A2[go]=a;
    }
    __syncthreads();   // previous iteration's LA2 reads done
    #pragma unroll
    for(int g=0;g<8;g++)
      #pragma unroll
      for(int r=0;r<4;r++)
        LA2[g][q*4+r][w*16+m] = f2bf(A2[g][r]);
    __syncthreads();
    // PV: wave w handles output heads 2w, 2w+1 over the full 64-wide j-tile
    #pragma unroll
    for(int sub=0;sub<2;sub++){
      const int g = w*2+sub;
      s16x8 a0 = *(const s16x8*)(&LA2[g][m][q*8]);
      s16x8 a1 = *(const s16x8*)(&LA2[g][m][32+q*8]);
      #pragma unroll
      for(int nt=0;nt<4;nt++){
        const unsigned short* vp = Vb + ((size_t)g*DH + nt*16 + m)*NP + jt*64 + q*8;
        s16x8 b0 = *(const s16x8*)(vp);
        s16x8 b1 = *(const s16x8*)(vp + 32);
        Oacc[sub][nt] = mfma16(a0, b0, Oacc[sub][nt]);
        Oacc[sub][nt] = mfma16(a1, b1, Oacc[sub][nt]);
      }
    }
  }
  // epilogue: O[b,p, g*64+d] bf16
  #pragma unroll
  for(int sub=0;sub<2;sub++){
    const int g = w*2+sub;
    #pragma unroll
    for(int nt=0;nt<4;nt++)
      #pragma unroll
      for(int r=0;r<4;r++)
        O[((size_t)b*NP + i0 + q*4 + r)*DM + g*DH + nt*16 + m] = f2bf(Oacc[sub][nt][r]);
  }
}

// ---------------- output projection ----------------
__global__ __launch_bounds__(256) void oproj_kern(const unsigned short* __restrict__ O,
    const unsigned short* __restrict__ WT, float* __restrict__ out){
  const int nb = blockIdx.y;
  const int R0 = blockIdx.x*64;
  const int tid = threadIdx.x;
  const int w = tid>>6, lane = tid&63, m = lane&15, q = lane>>4;
  const unsigned short* Wp = WT + (size_t)3*DM*DM;
  f32x4 acc[4] = {};
  const unsigned short* arow = O + (size_t)(R0 + w*16 + m)*DM + q*8;
  const unsigned short* brow = Wp + (size_t)(nb*64 + m)*DM + q*8;
  for(int k=0;k<DM;k+=32){
    s16x8 A = *(const s16x8*)(arow + k);
    #pragma unroll
    for(int nt=0;nt<4;nt++){
      s16x8 B = *(const s16x8*)(brow + (size_t)nt*16*DM + k);
      acc[nt] = mfma16(A, B, acc[nt]);
    }
  }
  #pragma unroll
  for(int nt=0;nt<4;nt++)
    #pragma unroll
    for(int r=0;r<4;r++)
      out[(size_t)(R0 + w*16 + q*4 + r)*DM + nb*64 + nt*16 + m] = acc[nt][r];
}

extern "C" void kernel_launch(void* const* d_in, const int* in_sizes, int n_in,
                              void* d_out, int out_size, void* d_ws, size_t ws_size,
                              hipStream_t stream){
  (void)in_sizes; (void)n_in; (void)out_size; (void)ws_size;
  const float* x  = (const float*)d_in[0];
  const float* Wq = (const float*)d_in[1];
  const float* Wk = (const float*)d_in[2];
  const float* Wv = (const float*)d_in[3];
  const float* W1 = (const float*)d_in[4];
  const float* W2 = (const float*)d_in[5];
  const float* Wp = (const float*)d_in[6];

  char* ws = (char*)d_ws;
  unsigned short* xb = (unsigned short*)ws;  ws += (size_t)NROWS*DM*2;   // 4 MB
  unsigned short* WT = (unsigned short*)ws;  ws += (size_t)4*DM*DM*2;    // 2 MB
  unsigned short* Qs = (unsigned short*)ws;  ws += (size_t)NB*NH*NP*DH*2; // 4 MB
  unsigned short* Kk = (unsigned short*)ws;  ws += (size_t)NB*NH*NP*DH*2; // 4 MB
  unsigned short* Vt = (unsigned short*)ws;  ws += (size_t)NB*NH*DH*NP*2; // 4 MB
  unsigned short* O  = (unsigned short*)ws;  ws += (size_t)NROWS*DM*2;   // 4 MB

  prep_x<<<NROWS*DM/1024, 256, 0, stream>>>(x, xb);
  prep_w<<<dim3(8,8,4), 256, 0, stream>>>(Wq, Wk, Wv, Wp, WT);
  qkv_kern<<<dim3(64,8,3), 256, 0, stream>>>(xb, WT, Qs, Kk, Vt);
  attn_kern<<<dim3(128,2), 256, 0, stream>>>(Qs, Kk, Vt, W1, W2, O);
  oproj_kern<<<dim3(64,8), 256, 0, stream>>>(O, WT, (float*)d_out);
}